// Round 8
// baseline (347.514 us; speedup 1.0000x reference)
//
#include <hip/hip_runtime.h>
#include <math.h>

#define Bn 512
#define Ln 20
#define Nn 100
#define Dn 64
#define En 32
#define Hn 3

// ---------------- K0_fold: LDS-staged folded weight products ----------------
// grid = Hn*4; block (h, sub) computes quarter-range of WMr/GuT/GiT for head h.
// All operand reads are LDS (broadcast or consecutive) — no strided global loads.
__global__ __launch_bounds__(256) void k0_fold(
    const float* __restrict__ M_r, const float* __restrict__ Wu_r, const float* __restrict__ bu_r,
    const float* __restrict__ M_w, const float* __restrict__ Wu_w, const float* __restrict__ bu_w,
    const float* __restrict__ Wi_w, const float* __restrict__ bi_w,
    float* __restrict__ WMr, float* __restrict__ bMr,
    float* __restrict__ GuT, float* __restrict__ GiT,
    float* __restrict__ gu_v, float* __restrict__ gi_v)
{
    __shared__ float A[4096], B2[4096], C2[4096], D2[4096], E2[4096];
    __shared__ float MBs[64], MTBs[64];
    int tid = threadIdx.x;
    int h = blockIdx.x >> 2, sub = blockIdx.x & 3;
    // ---- stage M_w, Wu_w, Wi_w ----
    {
        const float4* a = (const float4*)(M_w + h*4096);
        const float4* bsrc = (const float4*)(Wu_w + h*4096);
        const float4* c = (const float4*)(Wi_w + h*4096);
        for (int k = tid; k < 1024; k += 256) {
            ((float4*)A)[k] = a[k];
            ((float4*)B2)[k] = bsrc[k];
            ((float4*)C2)[k] = c[k];
        }
    }
    __syncthreads();
    // ---- P[d][b] = sum_e M_w[d][e]*Wi_w[e][b] -> D2 ; Q[d][b] = sum_e M_w[e][d]*Wu_w[e][b] -> E2 (full) ----
    for (int k = tid; k < 4096; k += 256) {
        int d = k >> 6, b = k & 63;
        float p = 0.f, q = 0.f;
        for (int e = 0; e < 64; ++e) {
            p += A[d*64 + e] * C2[e*64 + b];   // A[d][e] broadcast, C2 consecutive
            q += A[e*64 + d] * B2[e*64 + b];
        }
        D2[k] = p; E2[k] = q;
    }
    if (sub == 0 && tid < 64) {
        float p = 0.f, q = 0.f;
        for (int e = 0; e < 64; ++e) {
            p += A[tid*64 + e] * bi_w[h*64 + e];   // MB[d]
            q += A[e*64 + tid] * bu_w[h*64 + e];   // MTB[d]
        }
        MBs[tid] = p; MTBs[tid] = q;
    }
    __syncthreads();
    // ---- GuT[b][a] = sum_d Wu_w[d][a]*P[d][b] ; GiT[b][a] = sum_d Wi_w[d][a]*Q[d][b] (sub range) ----
    #pragma unroll
    for (int i = 0; i < 4; ++i) {
        int k = sub*1024 + i*256 + tid;
        int b = k >> 6, a = k & 63;
        float s1 = 0.f, s2 = 0.f;
        for (int d = 0; d < 64; ++d) {
            s1 += B2[d*64 + a] * D2[d*64 + b];     // B2 consecutive, D2 broadcast
            s2 += C2[d*64 + a] * E2[d*64 + b];
        }
        GuT[h*4096 + k] = s1; GiT[h*4096 + k] = s2;
    }
    if (sub == 0 && tid < 64) {
        float s1 = 0.f, s2 = 0.f;
        for (int d = 0; d < 64; ++d) {
            s1 += B2[d*64 + tid] * MBs[d];
            s2 += C2[d*64 + tid] * MTBs[d];
        }
        gu_v[h*64 + tid] = s1; gi_v[h*64 + tid] = s2;
    }
    __syncthreads();
    // ---- restage M_r, Wu_r; WMr[c][e] = sum_d Wu_r[d][c]*M_r[d][e] ----
    {
        const float4* a = (const float4*)(M_r + h*4096);
        const float4* bsrc = (const float4*)(Wu_r + h*4096);
        for (int k = tid; k < 1024; k += 256) {
            ((float4*)A)[k] = a[k];
            ((float4*)B2)[k] = bsrc[k];
        }
    }
    __syncthreads();
    #pragma unroll
    for (int i = 0; i < 4; ++i) {
        int k = sub*1024 + i*256 + tid;
        int c = k >> 6, e = k & 63;
        float s = 0.f;
        for (int d = 0; d < 64; ++d) s += B2[d*64 + c] * A[d*64 + e];  // broadcast, consecutive
        WMr[h*4096 + k] = s;
    }
    if (sub == 0 && tid < 64) {
        float s = 0.f;
        for (int d = 0; d < 64; ++d) s += bu_r[h*64 + d] * A[d*64 + tid];
        bMr[h*64 + tid] = s;
    }
}

// ---------------- K0_misc: small transposes ----------------
__global__ __launch_bounds__(256) void k0_misc(
    const float* __restrict__ Wi_r,
    const float* __restrict__ Wu_f, const float* __restrict__ Wi_f,
    const float* __restrict__ ufc, const float* __restrict__ ifc,
    const float* __restrict__ ufc2, const float* __restrict__ ifc2,
    float* __restrict__ WiT_r,
    float* __restrict__ WuT_f, float* __restrict__ WiT_f,
    float* __restrict__ ufcT, float* __restrict__ ifcT,
    float* __restrict__ u_fcT, float* __restrict__ i_fcT)
{
    int t = blockIdx.x * blockDim.x + threadIdx.x;
    int stride = gridDim.x * blockDim.x;
    for (int k = t; k < Hn*Dn*Dn; k += stride) {
        int h = k >> 12, r = k & 4095; int c = r >> 6, dp = r & 63;
        WiT_r[k] = Wi_r[h*4096 + dp*Dn + c];
    }
    for (int k = t; k < Hn*En*En; k += stride) {
        int h = k / (En*En); int rem = k - h*En*En;
        int a = rem >> 5, c = rem & 31;
        int src = h*En*En + c*En + a;
        WuT_f[k] = Wu_f[src]; WiT_f[k] = Wi_f[src];
    }
    for (int k = t; k < Dn*En; k += stride) {
        int d = k >> 5, e = k & 31;
        ufcT[k] = ufc[e*Dn + d]; ifcT[k] = ifc[e*Dn + d];
    }
    for (int k = t; k < 96*En; k += stride) {
        int kk = k >> 5, e = k & 31;
        u_fcT[k] = ufc2[e*96 + kk]; i_fcT[k] = ifc2[e*96 + kk];
    }
}

// ---------------- K1a: gather-sum only ----------------
__global__ __launch_bounds__(256) void k1a_gsum(
    const int* __restrict__ urev, const int* __restrict__ irev,
    const float* __restrict__ utab, const float* __restrict__ itab,
    float* __restrict__ sout)
{
    int tid = threadIdx.x;
    int ln = tid & 63;
    int wv = tid >> 6;
    int gw = blockIdx.x * 4 + wv;
    int side = (gw >= Bn*Ln);
    int r = gw - (side ? Bn*Ln : 0);
    const int* rev = side ? irev : urev;
    const float* tab = side ? itab : utab;
    int i0 = rev[r*Nn + ln];
    int i1 = (ln < Nn - 64) ? rev[r*Nn + 64 + ln] : 0;
    int r0 = ln >> 4;
    int q4 = (ln & 15) << 2;
    float4 buf[25];
    #pragma unroll
    for (int j = 0; j < 25; ++j) {
        int n = r0 + 4*j;
        int idx = (n < 64) ? __shfl(i0, n) : __shfl(i1, n - 64);
        buf[j] = *(const float4*)(tab + idx*Dn + q4);
    }
    float4 a = buf[0];
    #pragma unroll
    for (int j = 1; j < 25; ++j) { a.x += buf[j].x; a.y += buf[j].y; a.z += buf[j].z; a.w += buf[j].w; }
    a.x += __shfl_xor(a.x, 16); a.y += __shfl_xor(a.y, 16); a.z += __shfl_xor(a.z, 16); a.w += __shfl_xor(a.w, 16);
    a.x += __shfl_xor(a.x, 32); a.y += __shfl_xor(a.y, 32); a.z += __shfl_xor(a.z, 32); a.w += __shfl_xor(a.w, 32);
    if (ln < 16) *(float4*)(sout + gw*Dn + q4) = a;
}

// ---------------- K1b: gate MLP on dense gather-sums ----------------
__global__ __launch_bounds__(256) void k1b_gate(
    const float* __restrict__ sin,
    const float* __restrict__ W1, const float* __restrict__ b1v,
    const float* __restrict__ W2, const float* __restrict__ b2v,
    float* __restrict__ ugo, float* __restrict__ igo)
{
    __shared__ float w1s[Dn][Dn+1];
    __shared__ float w2s[Dn][Dn+1];
    int tid = threadIdx.x;
    for (int k = tid; k < Dn*Dn; k += 256) {
        int r = k >> 6, c = k & 63;
        w1s[r][c] = W1[k]; w2s[r][c] = W2[k];
    }
    __syncthreads();
    int ln = tid & 63;
    int wv = tid >> 6;
    float b1 = b1v[ln], b2 = b2v[ln];
    int nW = gridDim.x * 4;
    for (int gw = blockIdx.x * 4 + wv; gw < 2*Bn*Ln; gw += nW) {
        float sv = sin[gw*Dn + ln];
        float t1 = b1, t2 = b2;
        #pragma unroll 8
        for (int d = 0; d < Dn; ++d) {
            float sd = __shfl(sv, d);
            t1 += sd * w1s[ln][d];
            t2 += sd * w2s[ln][d];
        }
        float g = (1.f / (1.f + expf(-t1))) * tanhf(t2);
        int side = (gw >= Bn*Ln);
        int r = gw - (side ? Bn*Ln : 0);
        (side ? igo : ugo)[r*Dn + ln] = g;
    }
}

// ---------------- K2 v3: per-(b,h) pipeline, 28KB LDS, 4 blocks/CU ----------------
__global__ __launch_bounds__(256, 4) void k2_coatt(
    const int* __restrict__ urev, const int* __restrict__ irev,
    const int* __restrict__ uids, const int* __restrict__ iids,
    const int* __restrict__ ttype, const int* __restrict__ tmonth,
    const float* __restrict__ gu_all, const float* __restrict__ gi_all,
    const float* __restrict__ utab, const float* __restrict__ itab,
    const float* __restrict__ uid_tab, const float* __restrict__ iid_tab,
    const float* __restrict__ type_tab, const float* __restrict__ month_tab,
    const float* __restrict__ ug_in, const float* __restrict__ ig_in,
    const float* __restrict__ WMr, const float* __restrict__ bMr,
    const float* __restrict__ WiT_r, const float* __restrict__ bi_r,
    const float* __restrict__ GuT, const float* __restrict__ GiT,
    const float* __restrict__ gu_v, const float* __restrict__ gi_v,
    const float* __restrict__ M_f, const float* __restrict__ bu_f, const float* __restrict__ bi_f,
    const float* __restrict__ WuT_f, const float* __restrict__ WiT_f,
    const float* __restrict__ ufcT, const float* __restrict__ ufc_bv,
    const float* __restrict__ ifcT, const float* __restrict__ ifc_bv,
    float* __restrict__ feas, float* __restrict__ outp)
{
    __shared__ __align__(16) float pool[6400];
    __shared__ float vecs[4][Dn];   // uwbar, iwbar, wu, wi
    __shared__ float sc[2][Nn];
    __shared__ float uif[2][Dn];
    __shared__ float att[6];
    __shared__ int   lstar[2];

    int tid = threadIdx.x;
    int bh = blockIdx.x;
    int b = bh / Hn;
    int h = bh - b*Hn;
    int ln = tid & 63;
    int wv = tid >> 6;

    // ---- phase 0: stage gates ----
    {
        const float4* su = (const float4*)(ug_in + b*Ln*Dn);
        const float4* si = (const float4*)(ig_in + b*Ln*Dn);
        float4* du = (float4*)pool;              // ug
        float4* di = (float4*)(pool + 1280);     // ig
        for (int k = tid; k < (Ln*Dn)/4; k += 256) { du[k] = su[k]; di[k] = si[k]; }
    }
    __syncthreads();

    // ---- phase 1: Ab = ug@WMr + bMr ; iv = ig@WiT_r + bi ----
    {
        int iside = wv >> 1;
        int lbase = (wv & 1) * 10;
        const float* W = (iside ? (WiT_r + h*4096) : (WMr + h*4096)) + ln;
        const float* X = pool + (iside ? 1280 : 0);
        float bias = iside ? bi_r[h*Dn + ln] : bMr[h*Dn + ln];
        float acc[10];
        #pragma unroll
        for (int l = 0; l < 10; ++l) acc[l] = 0.f;
        for (int dd = 0; dd < Dn; dd += 4) {
            float w0 = W[(dd+0)*Dn];
            float w1 = W[(dd+1)*Dn];
            float w2 = W[(dd+2)*Dn];
            float w3 = W[(dd+3)*Dn];
            #pragma unroll
            for (int l = 0; l < 10; ++l) {
                float4 x = *(const float4*)(X + (lbase+l)*Dn + dd);
                acc[l] += x.x*w0 + x.y*w1 + x.z*w2 + x.w*w3;
            }
        }
        float* out = pool + (iside ? 3840 : 2560);
        #pragma unroll
        for (int l = 0; l < 10; ++l) {
            int lg = lbase + l;
            out[lg*Dn + (ln ^ lg)] = acc[l] + bias;
        }
    }
    __syncthreads();
    for (int k = tid; k < Ln*Ln; k += 256) {
        int l = k / Ln, m = k - l*Ln;
        const float* Ab = pool + 2560 + l*Dn;
        const float* iv = pool + 3840 + m*Dn;
        float a = 0.f;
        for (int e = 0; e < Dn; ++e) a += Ab[e ^ l] * iv[e ^ m];
        pool[5120 + k] = a;
    }
    __syncthreads();
    if (wv == 0) {
        float v = -3.4e38f;
        if (ln < Ln) {
            float mx = pool[5120 + ln*Ln];
            #pragma unroll
            for (int m = 1; m < Ln; ++m) mx = fmaxf(mx, pool[5120 + ln*Ln + m]);
            v = mx + gu_all[(h*Bn + b)*Ln + ln];
        }
        int idx = ln;
        #pragma unroll
        for (int off = 32; off > 0; off >>= 1) {
            float ov = __shfl_down(v, off);
            int oi = __shfl_down(idx, off);
            if (ov > v || (ov == v && oi < idx)) { v = ov; idx = oi; }
        }
        if (ln == 0) lstar[0] = idx;
    } else if (wv == 1) {
        float v = -3.4e38f;
        if (ln < Ln) {
            float mx = pool[5120 + ln];
            #pragma unroll
            for (int l = 1; l < Ln; ++l) mx = fmaxf(mx, pool[5120 + l*Ln + ln]);
            v = mx + gi_all[(h*Bn + b)*Ln + ln];
        }
        int idx = ln;
        #pragma unroll
        for (int off = 32; off > 0; off >>= 1) {
            float ov = __shfl_down(v, off);
            int oi = __shfl_down(idx, off);
            if (ov > v || (ov == v && oi < idx)) { v = ov; idx = oi; }
        }
        if (ln == 0) lstar[1] = idx;
    }
    __syncthreads();

    int rubase = (b*Ln + lstar[0])*Nn;
    int ribase = (b*Ln + lstar[1])*Nn;
    int r0 = ln >> 4;
    int q4 = (ln & 15) << 2;
    int idxr[25];

    if (wv < 2) {
        for (int k = tid; k < Nn*16; k += 128) {
            int n = k >> 4, qi = k & 15;
            int idx = urev[rubase + n];
            float4 v = *(const float4*)(utab + idx*Dn + (qi << 2));
            *(float4*)(pool + n*Dn + (((qi ^ (n & 15)) << 2))) = v;
        }
    } else {
        const int* rev = (wv == 2) ? irev : urev;
        const float* tab = (wv == 2) ? itab : utab;
        int rb = (wv == 2) ? ribase : rubase;
        #pragma unroll
        for (int j = 0; j < 25; ++j) idxr[j] = rev[rb + r0 + 4*j];
        float4 s = make_float4(0.f, 0.f, 0.f, 0.f);
        #pragma unroll 5
        for (int g = 0; g < 5; ++g) {
            float4 v0 = *(const float4*)(tab + idxr[g*5+0]*Dn + q4);
            float4 v1 = *(const float4*)(tab + idxr[g*5+1]*Dn + q4);
            float4 v2 = *(const float4*)(tab + idxr[g*5+2]*Dn + q4);
            float4 v3 = *(const float4*)(tab + idxr[g*5+3]*Dn + q4);
            float4 v4 = *(const float4*)(tab + idxr[g*5+4]*Dn + q4);
            s.x += v0.x+v1.x+v2.x+v3.x+v4.x;
            s.y += v0.y+v1.y+v2.y+v3.y+v4.y;
            s.z += v0.z+v1.z+v2.z+v3.z+v4.z;
            s.w += v0.w+v1.w+v2.w+v3.w+v4.w;
        }
        s.x += __shfl_xor(s.x, 16); s.y += __shfl_xor(s.y, 16); s.z += __shfl_xor(s.z, 16); s.w += __shfl_xor(s.w, 16);
        s.x += __shfl_xor(s.x, 32); s.y += __shfl_xor(s.y, 32); s.z += __shfl_xor(s.z, 32); s.w += __shfl_xor(s.w, 32);
        if (ln < 16) {
            float4 m = make_float4(s.x*(1.f/Nn), s.y*(1.f/Nn), s.z*(1.f/Nn), s.w*(1.f/Nn));
            *(float4*)(&vecs[(wv == 2) ? 1 : 0][q4]) = m;
        }
    }
    __syncthreads();

    if (tid < Dn) {
        float a = gu_v[h*Dn + tid];
        for (int bb = 0; bb < Dn; ++bb) a += GuT[h*4096 + bb*Dn + tid] * vecs[1][bb];
        vecs[2][tid] = a;
    } else if (tid < 2*Dn) {
        int aa = tid - Dn;
        float a = gi_v[h*Dn + aa];
        for (int bb = 0; bb < Dn; ++bb) a += GiT[h*4096 + bb*Dn + aa] * vecs[0][bb];
        vecs[3][aa] = a;
    }
    __syncthreads();

    if (tid < Nn) {
        float a = 0.f;
        const float* row = pool + tid*Dn;
        int sw = tid & 15;
        #pragma unroll
        for (int qi = 0; qi < 16; ++qi) {
            float4 w = *(const float4*)(&vecs[2][qi << 2]);
            float4 x = *(const float4*)(row + ((qi ^ sw) << 2));
            a += x.x*w.x + x.y*w.y + x.z*w.z + x.w*w.w;
        }
        sc[0][tid] = a;
    } else if (wv == 2) {
        float4 wq = *(const float4*)(&vecs[3][q4]);
        #pragma unroll 5
        for (int g = 0; g < 5; ++g) {
            float p0, p1, p2, p3, p4;
            {
                float4 v0 = *(const float4*)(itab + idxr[g*5+0]*Dn + q4);
                float4 v1 = *(const float4*)(itab + idxr[g*5+1]*Dn + q4);
                float4 v2 = *(const float4*)(itab + idxr[g*5+2]*Dn + q4);
                float4 v3 = *(const float4*)(itab + idxr[g*5+3]*Dn + q4);
                float4 v4 = *(const float4*)(itab + idxr[g*5+4]*Dn + q4);
                p0 = v0.x*wq.x + v0.y*wq.y + v0.z*wq.z + v0.w*wq.w;
                p1 = v1.x*wq.x + v1.y*wq.y + v1.z*wq.z + v1.w*wq.w;
                p2 = v2.x*wq.x + v2.y*wq.y + v2.z*wq.z + v2.w*wq.w;
                p3 = v3.x*wq.x + v3.y*wq.y + v3.z*wq.z + v3.w*wq.w;
                p4 = v4.x*wq.x + v4.y*wq.y + v4.z*wq.z + v4.w*wq.w;
            }
            #pragma unroll
            for (int off = 1; off < 16; off <<= 1) {
                p0 += __shfl_xor(p0, off); p1 += __shfl_xor(p1, off);
                p2 += __shfl_xor(p2, off); p3 += __shfl_xor(p3, off);
                p4 += __shfl_xor(p4, off);
            }
            if ((ln & 15) == 0) {
                sc[1][r0 + 4*(g*5+0)] = p0;
                sc[1][r0 + 4*(g*5+1)] = p1;
                sc[1][r0 + 4*(g*5+2)] = p2;
                sc[1][r0 + 4*(g*5+3)] = p3;
                sc[1][r0 + 4*(g*5+4)] = p4;
            }
        }
    }
    __syncthreads();
    if (wv == 0 || wv == 2) {
        float* s = sc[wv >> 1];
        float x0 = s[ln];
        float x1 = (ln < Nn - 64) ? s[64 + ln] : -3.4e38f;
        float mx = fmaxf(x0, x1);
        #pragma unroll
        for (int off = 32; off > 0; off >>= 1) mx = fmaxf(mx, __shfl_xor(mx, off));
        float e0 = expf(x0 - mx);
        float e1 = (ln < Nn - 64) ? expf(x1 - mx) : 0.f;
        float sum = e0 + e1;
        #pragma unroll
        for (int off = 32; off > 0; off >>= 1) sum += __shfl_xor(sum, off);
        float inv = 1.f / sum;
        s[ln] = e0 * inv;
        if (ln < Nn - 64) s[64 + ln] = e1 * inv;
    }
    __syncthreads();
    if (tid < 2*Dn) {
        int which = tid >> 6;
        int d = tid & 63;
        int qt = (d >> 2), dl = d & 3;
        const float* p = sc[which];
        float a = 0.f;
        for (int n = 0; n < Nn; ++n)
            a += p[n] * pool[n*Dn + ((qt ^ (n & 15)) << 2) + dl];
        uif[which][d] = a;
    }
    __syncthreads();
    float* fe_ = pool;
    float* re_ = pool + 128;
    float* u3_ = pool + 192;
    float* i3_ = pool + 256;
    float* A3_ = pool + 384;
    if (tid < En) {
        float a = ufc_bv[tid];
        for (int d = 0; d < Dn; ++d) a += uif[0][d] * ufcT[d*En + tid];
        re_[tid] = fmaxf(a, 0.f);
    } else if (tid < 2*En) {
        int e = tid - En;
        float a = ifc_bv[e];
        for (int d = 0; d < Dn; ++d) a += uif[1][d] * ifcT[d*En + e];
        re_[En + e] = fmaxf(a, 0.f);
    } else if (tid < 2*En + 4*En) {
        int j = tid - 2*En;
        int rrow = j >> 5, e = j & 31;
        float v;
        if (rrow == 0) v = uid_tab[uids[b]*En + e];
        else if (rrow == 1) v = iid_tab[iids[b]*En + e];
        else if (rrow == 2) v = type_tab[ttype[b]*En + e];
        else v = month_tab[tmonth[b]*En + e];
        fe_[j] = v;
    }
    __syncthreads();
    const float* WuTf = WuT_f + h*En*En;
    const float* WiTf = WiT_f + h*En*En;
    const float* Mf   = M_f  + h*En*En;
    if (tid < 2*En) {
        int l = tid >> 5, e = tid & 31;
        float a = bu_f[h*En + e];
        for (int j = 0; j < En; ++j) a += re_[l*En + j] * WuTf[j*En + e];
        u3_[tid] = a;
    } else if (tid < 6*En) {
        int t2 = tid - 2*En;
        int m = t2 >> 5, e = t2 & 31;
        float a = bi_f[h*En + e];
        for (int j = 0; j < En; ++j) a += fe_[m*En + j] * WiTf[j*En + e];
        i3_[t2] = a;
    }
    __syncthreads();
    if (tid < 2*En) {
        int l = tid >> 5, e = tid & 31;
        float a = 0.f;
        for (int d = 0; d < En; ++d) a += u3_[l*En + d] * Mf[d*En + e];
        A3_[tid] = a;
    }
    __syncthreads();
    if (tid == 0) {
        float S3[2][4];
        for (int l = 0; l < 2; ++l)
            for (int m = 0; m < 4; ++m) {
                float a = 0.f;
                for (int e = 0; e < En; ++e) a += A3_[l*En + e] * i3_[m*En + e];
                S3[l][m] = a;
            }
        float us0 = (S3[0][0] + S3[0][1] + S3[0][2] + S3[0][3]) * 0.25f;
        float us1 = (S3[1][0] + S3[1][1] + S3[1][2] + S3[1][3]) * 0.25f;
        float mx = fmaxf(us0, us1);
        float e0 = expf(us0 - mx), e1 = expf(us1 - mx);
        float inv = 1.f / (e0 + e1);
        att[0] = e0 * inv; att[1] = e1 * inv;
        float is_[4]; float mxi = -3.4e38f;
        for (int m = 0; m < 4; ++m) { is_[m] = (S3[0][m] + S3[1][m]) * 0.5f; mxi = fmaxf(mxi, is_[m]); }
        float ssum = 0.f, ee[4];
        for (int m = 0; m < 4; ++m) { ee[m] = expf(is_[m] - mxi); ssum += ee[m]; }
        float invi = 1.f / ssum;
        for (int m = 0; m < 4; ++m) att[2 + m] = ee[m] * invi;
    }
    __syncthreads();
    if (tid < En) {
        feas[b*96 + h*En + tid] = re_[tid] * att[0];
    }
    if (h == 2) {
        if (tid >= 32 && tid < 64)        { int e = tid - 32;  outp[b*96 + e]              = fe_[e]      * att[2]; }
        else if (tid >= 64 && tid < 96)   { int e = tid - 64;  outp[b*96 + 32 + e]         = fe_[64 + e] * att[4]; }
        else if (tid >= 96 && tid < 128)  { int e = tid - 96;  outp[Bn*96 + b*96 + e]      = fe_[32 + e] * att[3]; }
        else if (tid >= 128 && tid < 160) { int e = tid - 128; outp[Bn*96 + b*96 + 32 + e] = fe_[96 + e] * att[5]; }
    }
}

// ---------------- K3: final linears ----------------
__global__ __launch_bounds__(64) void k3_final(
    const float* __restrict__ feas,
    const float* __restrict__ u_fcT, const float* __restrict__ u_fc_bv,
    const float* __restrict__ i_fcT, const float* __restrict__ i_fc_bv,
    float* __restrict__ outp)
{
    __shared__ float f[96];
    int b = blockIdx.x, tid = threadIdx.x;
    for (int k = tid; k < 96; k += 64) f[k] = feas[b*96 + k];
    __syncthreads();
    if (tid < 32) {
        float a = u_fc_bv[tid];
        for (int k = 0; k < 96; ++k) a += f[k] * u_fcT[k*32 + tid];
        outp[b*96 + 64 + tid] = a;
    } else {
        int e = tid - 32;
        float a = i_fc_bv[e];
        for (int k = 0; k < 96; ++k) a += f[k] * i_fcT[k*32 + e];
        outp[Bn*96 + b*96 + 64 + e] = a;
    }
}

extern "C" void kernel_launch(void* const* d_in, const int* in_sizes, int n_in,
                              void* d_out, int out_size, void* d_ws, size_t ws_size,
                              hipStream_t stream)
{
    const int* urev = (const int*)d_in[0];
    const int* irev = (const int*)d_in[1];
    const int* uids = (const int*)d_in[2];
    const int* iids = (const int*)d_in[3];
    const int* ttype = (const int*)d_in[4];
    const int* tmonth = (const int*)d_in[5];
    const float* gu = (const float*)d_in[6];
    const float* gi = (const float*)d_in[7];
    const float* utab = (const float*)d_in[8];
    const float* itab = (const float*)d_in[9];
    const float* uid_tab = (const float*)d_in[10];
    const float* iid_tab = (const float*)d_in[11];
    const float* type_tab = (const float*)d_in[12];
    const float* month_tab = (const float*)d_in[13];
    const float* fc_g1_w = (const float*)d_in[14];
    const float* fc_g1_b = (const float*)d_in[15];
    const float* fc_g2_w = (const float*)d_in[16];
    const float* fc_g2_b = (const float*)d_in[17];
    const float* M_r = (const float*)d_in[18];
    const float* Wu_r = (const float*)d_in[19];
    const float* bu_r = (const float*)d_in[20];
    const float* Wi_r = (const float*)d_in[21];
    const float* bi_r = (const float*)d_in[22];
    const float* M_w = (const float*)d_in[23];
    const float* Wu_w = (const float*)d_in[24];
    const float* bu_w = (const float*)d_in[25];
    const float* Wi_w = (const float*)d_in[26];
    const float* bi_w = (const float*)d_in[27];
    const float* M_f = (const float*)d_in[28];
    const float* Wu_f = (const float*)d_in[29];
    const float* bu_f = (const float*)d_in[30];
    const float* Wi_f = (const float*)d_in[31];
    const float* bi_f = (const float*)d_in[32];
    const float* ufc_w = (const float*)d_in[33];
    const float* ufc_b = (const float*)d_in[34];
    const float* ifc_w = (const float*)d_in[35];
    const float* ifc_b = (const float*)d_in[36];
    const float* u_fc_w = (const float*)d_in[37];
    const float* u_fc_b = (const float*)d_in[38];
    const float* i_fc_w = (const float*)d_in[39];
    const float* i_fc_b = (const float*)d_in[40];
    (void)in_sizes; (void)n_in; (void)out_size; (void)ws_size;

    float* ws = (float*)d_ws;
    float* ugo   = ws;
    float* igo   = ugo + Bn*Ln*Dn;
    float* sgat  = igo + Bn*Ln*Dn;
    float* feas  = sgat + 2*Bn*Ln*Dn;
    float* WiT_r = feas + Bn*96;
    float* WMr   = WiT_r + Hn*Dn*Dn;
    float* bMr   = WMr + Hn*Dn*Dn;
    float* GuT   = bMr + Hn*Dn;
    float* GiT   = GuT + Hn*Dn*Dn;
    float* gu_v  = GiT + Hn*Dn*Dn;
    float* gi_v  = gu_v + Hn*Dn;
    float* WuT_f = gi_v + Hn*Dn;
    float* WiT_f = WuT_f + Hn*En*En;
    float* ufcT  = WiT_f + Hn*En*En;
    float* ifcT  = ufcT + Dn*En;
    float* u_fcT = ifcT + Dn*En;
    float* i_fcT = u_fcT + 96*En;

    hipLaunchKernelGGL(k0_fold, dim3(Hn*4), dim3(256), 0, stream,
        M_r, Wu_r, bu_r, M_w, Wu_w, bu_w, Wi_w, bi_w,
        WMr, bMr, GuT, GiT, gu_v, gi_v);

    hipLaunchKernelGGL(k0_misc, dim3(16), dim3(256), 0, stream,
        Wi_r, Wu_f, Wi_f, ufc_w, ifc_w, u_fc_w, i_fc_w,
        WiT_r, WuT_f, WiT_f, ufcT, ifcT, u_fcT, i_fcT);

    hipLaunchKernelGGL(k1a_gsum, dim3(2*Bn*Ln/4), dim3(256), 0, stream,
        urev, irev, utab, itab, sgat);

    hipLaunchKernelGGL(k1b_gate, dim3(512), dim3(256), 0, stream,
        sgat, fc_g1_w, fc_g1_b, fc_g2_w, fc_g2_b, ugo, igo);

    hipLaunchKernelGGL(k2_coatt, dim3(Bn*Hn), dim3(256), 0, stream,
        urev, irev, uids, iids, ttype, tmonth, gu, gi, utab, itab,
        uid_tab, iid_tab, type_tab, month_tab, ugo, igo,
        WMr, bMr, WiT_r, bi_r, GuT, GiT, gu_v, gi_v,
        M_f, bu_f, bi_f, WuT_f, WiT_f,
        ufcT, ufc_b, ifcT, ifc_b, feas, (float*)d_out);

    hipLaunchKernelGGL(k3_final, dim3(Bn), dim3(64), 0, stream,
        feas, u_fcT, u_fc_b, i_fcT, i_fc_b, (float*)d_out);
}

// Round 9
// 292.617 us; speedup vs baseline: 1.1876x; 1.1876x over previous
//
#include <hip/hip_runtime.h>
#include <math.h>

#define Bn 512
#define Ln 20
#define Nn 100
#define Dn 64
#define En 32
#define Hn 3

// ---------------- K0_all: all weight prep in ONE launch (203 blocks) ----------------
// blocks [0,48):   WMr[h][c][e] = sum_d Wu_r[h][d][c]*M_r[h][d][e]   (wave per (h,c))
// blocks [48,51):  bMr[h][e]
// blocks [51,147): GuT/GiT via double contraction + gu_v/gi_v        (wave per (h,a))
// blocks [147,195): WiT_r transpose
// blocks [195,203): misc small transposes (grid-stride)
__global__ __launch_bounds__(256) void k0_all(
    const float* __restrict__ M_r, const float* __restrict__ Wu_r, const float* __restrict__ bu_r,
    const float* __restrict__ Wi_r,
    const float* __restrict__ M_w, const float* __restrict__ Wu_w, const float* __restrict__ bu_w,
    const float* __restrict__ Wi_w, const float* __restrict__ bi_w,
    const float* __restrict__ Wu_f, const float* __restrict__ Wi_f,
    const float* __restrict__ ufc, const float* __restrict__ ifc,
    const float* __restrict__ ufc2, const float* __restrict__ ifc2,
    float* __restrict__ WMr, float* __restrict__ bMr,
    float* __restrict__ GuT, float* __restrict__ GiT,
    float* __restrict__ gu_v, float* __restrict__ gi_v,
    float* __restrict__ WiT_r,
    float* __restrict__ WuT_f, float* __restrict__ WiT_f,
    float* __restrict__ ufcT, float* __restrict__ ifcT,
    float* __restrict__ u_fcT, float* __restrict__ i_fcT)
{
    __shared__ float tbuf[4][64];
    int tid = threadIdx.x, ln = tid & 63, wv = tid >> 6;
    int blk = blockIdx.x;
    if (blk < 48) {                       // WMr
        int W = blk*4 + wv;               // [0,192)
        int h = W >> 6, c = W & 63;
        const float* Wu = Wu_r + h*4096;
        const float* M  = M_r  + h*4096;
        float s = 0.f;
        for (int d = 0; d < 64; ++d) s += Wu[d*64 + c] * M[d*64 + ln];
        WMr[h*4096 + c*64 + ln] = s;
    } else if (blk < 51) {                // bMr
        int h = blk - 48;
        if (wv == 0) {
            float s = 0.f;
            for (int d = 0; d < 64; ++d) s += bu_r[h*64 + d] * M_r[h*4096 + d*64 + ln];
            bMr[h*64 + ln] = s;
        }
    } else if (blk < 147) {               // GuT / GiT / gu_v / gi_v
        int W = (blk - 51)*4 + wv;        // [0,384)
        int isGi = (W >= 192);
        int W2 = W - (isGi ? 192 : 0);
        int h = W2 >> 6, a = W2 & 63;
        float t;
        if (!isGi) {                      // t[e] = sum_d Wu_w[d][a]*M_w[d][e]
            const float* Wu = Wu_w + h*4096; const float* M = M_w + h*4096;
            t = 0.f;
            for (int d = 0; d < 64; ++d) t += Wu[d*64 + a] * M[d*64 + ln];
        } else {                          // t2[e] = sum_d M_w[e][d]*Wi_w[d][a]
            const float* Wi = Wi_w + h*4096; const float* M = M_w + h*4096;
            t = 0.f;
            for (int d = 0; d < 64; ++d) t += M[ln*64 + d] * Wi[d*64 + a];
        }
        tbuf[wv][ln] = t;                 // per-wave private LDS; intra-wave dep handled by lgkmcnt
        const float* Wsec = (isGi ? Wu_w : Wi_w) + h*4096;
        const float* bsec = (isGi ? bu_w : bi_w) + h*64;
        float s = 0.f, gvv = 0.f;
        for (int e = 0; e < 64; ++e) {
            float te = tbuf[wv][e];
            s   += te * Wsec[e*64 + ln];  // GuT[b=ln][a] = sum_e t[e]*Wi_w[e][b] (or Wu_w for Gi)
            gvv += te * bsec[e];
        }
        (isGi ? GiT : GuT)[h*4096 + ln*64 + a] = s;
        if (ln == 0) (isGi ? gi_v : gu_v)[h*64 + a] = gvv;
    } else if (blk < 195) {               // WiT_r[h][c][dp] = Wi_r[h][dp][c]
        int k = (blk - 147)*256 + tid;    // [0,12288)
        int h = k >> 12, r = k & 4095, c = r >> 6, dp = r & 63;
        WiT_r[k] = Wi_r[h*4096 + dp*64 + c];
    } else {                              // misc tail
        int t = (blk - 195)*256 + tid;
        int stride = 8*256;
        for (int k = t; k < Hn*En*En; k += stride) {
            int h = k/(En*En); int rem = k - h*En*En;
            int aa = rem >> 5, c = rem & 31;
            int src = h*En*En + c*En + aa;
            WuT_f[k] = Wu_f[src]; WiT_f[k] = Wi_f[src];
        }
        for (int k = t; k < Dn*En; k += stride) {
            int d = k >> 5, e = k & 31;
            ufcT[k] = ufc[e*Dn + d]; ifcT[k] = ifc[e*Dn + d];
        }
        for (int k = t; k < 96*En; k += stride) {
            int kk = k >> 5, e = k & 31;
            u_fcT[k] = ufc2[e*96 + kk]; i_fcT[k] = ifc2[e*96 + kk];
        }
    }
}

// ---------------- K1: fused gather-sum + gate MLP (batched loads, LDS-broadcast MLP) ----------------
__global__ __launch_bounds__(256) void k1_gate2(
    const int* __restrict__ urev, const int* __restrict__ irev,
    const float* __restrict__ utab, const float* __restrict__ itab,
    const float* __restrict__ W1, const float* __restrict__ b1v,
    const float* __restrict__ W2, const float* __restrict__ b2v,
    float* __restrict__ ugo, float* __restrict__ igo)
{
    __shared__ float w1s[Dn][Dn+1];
    __shared__ float w2s[Dn][Dn+1];
    __shared__ float rowb[4][Dn];
    int tid = threadIdx.x;
    for (int k = tid; k < Dn*Dn; k += 256) {
        w1s[k>>6][k&63] = W1[k];
        w2s[k>>6][k&63] = W2[k];
    }
    __syncthreads();
    int ln = tid & 63, wv = tid >> 6;
    int wid = blockIdx.x * 4 + wv;            // [0, 5120)
    int r0 = ln >> 4, q4 = (ln & 15) << 2;
    float b1 = b1v[ln], b2 = b2v[ln];
    #pragma unroll 1
    for (int it = 0; it < 4; ++it) {
        int gw = wid + it * 5120;             // [0, 20480)
        int side = (gw >= Bn*Ln);
        int r = gw - (side ? Bn*Ln : 0);
        const int* rev = side ? irev : urev;
        const float* tab = side ? itab : utab;
        int i0 = rev[r*Nn + ln];
        int i1 = (ln < Nn - 64) ? rev[r*Nn + 64 + ln] : 0;
        float4 buf[25];
        #pragma unroll
        for (int j = 0; j < 25; ++j) {
            int n = r0 + 4*j;
            int idx = (n < 64) ? __shfl(i0, n) : __shfl(i1, n - 64);
            buf[j] = *(const float4*)(tab + idx*Dn + q4);
        }
        float4 a = buf[0];
        #pragma unroll
        for (int j = 1; j < 25; ++j) { a.x += buf[j].x; a.y += buf[j].y; a.z += buf[j].z; a.w += buf[j].w; }
        a.x += __shfl_xor(a.x, 16); a.y += __shfl_xor(a.y, 16); a.z += __shfl_xor(a.z, 16); a.w += __shfl_xor(a.w, 16);
        a.x += __shfl_xor(a.x, 32); a.y += __shfl_xor(a.y, 32); a.z += __shfl_xor(a.z, 32); a.w += __shfl_xor(a.w, 32);
        if (ln < 16) *(float4*)(&rowb[wv][q4]) = a;   // per-wave private; lgkmcnt orders vs reads below
        float t1 = b1, t2 = b2;
        #pragma unroll 8
        for (int d = 0; d < Dn; ++d) {
            float sd = rowb[wv][d];
            t1 += sd * w1s[ln][d];
            t2 += sd * w2s[ln][d];
        }
        float g = (1.f / (1.f + expf(-t1))) * tanhf(t2);
        (side ? igo : ugo)[r*Dn + ln] = g;
    }
}

// ---------------- K2 v3: per-(b,h) pipeline, 28KB LDS (unchanged from R7/R8) ----------------
__global__ __launch_bounds__(256, 4) void k2_coatt(
    const int* __restrict__ urev, const int* __restrict__ irev,
    const int* __restrict__ uids, const int* __restrict__ iids,
    const int* __restrict__ ttype, const int* __restrict__ tmonth,
    const float* __restrict__ gu_all, const float* __restrict__ gi_all,
    const float* __restrict__ utab, const float* __restrict__ itab,
    const float* __restrict__ uid_tab, const float* __restrict__ iid_tab,
    const float* __restrict__ type_tab, const float* __restrict__ month_tab,
    const float* __restrict__ ug_in, const float* __restrict__ ig_in,
    const float* __restrict__ WMr, const float* __restrict__ bMr,
    const float* __restrict__ WiT_r, const float* __restrict__ bi_r,
    const float* __restrict__ GuT, const float* __restrict__ GiT,
    const float* __restrict__ gu_v, const float* __restrict__ gi_v,
    const float* __restrict__ M_f, const float* __restrict__ bu_f, const float* __restrict__ bi_f,
    const float* __restrict__ WuT_f, const float* __restrict__ WiT_f,
    const float* __restrict__ ufcT, const float* __restrict__ ufc_bv,
    const float* __restrict__ ifcT, const float* __restrict__ ifc_bv,
    float* __restrict__ feas, float* __restrict__ outp)
{
    __shared__ __align__(16) float pool[6400];
    __shared__ float vecs[4][Dn];
    __shared__ float sc[2][Nn];
    __shared__ float uif[2][Dn];
    __shared__ float att[6];
    __shared__ int   lstar[2];

    int tid = threadIdx.x;
    int bh = blockIdx.x;
    int b = bh / Hn;
    int h = bh - b*Hn;
    int ln = tid & 63;
    int wv = tid >> 6;

    {
        const float4* su = (const float4*)(ug_in + b*Ln*Dn);
        const float4* si = (const float4*)(ig_in + b*Ln*Dn);
        float4* du = (float4*)pool;
        float4* di = (float4*)(pool + 1280);
        for (int k = tid; k < (Ln*Dn)/4; k += 256) { du[k] = su[k]; di[k] = si[k]; }
    }
    __syncthreads();

    {
        int iside = wv >> 1;
        int lbase = (wv & 1) * 10;
        const float* W = (iside ? (WiT_r + h*4096) : (WMr + h*4096)) + ln;
        const float* X = pool + (iside ? 1280 : 0);
        float bias = iside ? bi_r[h*Dn + ln] : bMr[h*Dn + ln];
        float acc[10];
        #pragma unroll
        for (int l = 0; l < 10; ++l) acc[l] = 0.f;
        for (int dd = 0; dd < Dn; dd += 4) {
            float w0 = W[(dd+0)*Dn];
            float w1 = W[(dd+1)*Dn];
            float w2 = W[(dd+2)*Dn];
            float w3 = W[(dd+3)*Dn];
            #pragma unroll
            for (int l = 0; l < 10; ++l) {
                float4 x = *(const float4*)(X + (lbase+l)*Dn + dd);
                acc[l] += x.x*w0 + x.y*w1 + x.z*w2 + x.w*w3;
            }
        }
        float* out = pool + (iside ? 3840 : 2560);
        #pragma unroll
        for (int l = 0; l < 10; ++l) {
            int lg = lbase + l;
            out[lg*Dn + (ln ^ lg)] = acc[l] + bias;
        }
    }
    __syncthreads();
    for (int k = tid; k < Ln*Ln; k += 256) {
        int l = k / Ln, m = k - l*Ln;
        const float* Ab = pool + 2560 + l*Dn;
        const float* iv = pool + 3840 + m*Dn;
        float a = 0.f;
        for (int e = 0; e < Dn; ++e) a += Ab[e ^ l] * iv[e ^ m];
        pool[5120 + k] = a;
    }
    __syncthreads();
    if (wv == 0) {
        float v = -3.4e38f;
        if (ln < Ln) {
            float mx = pool[5120 + ln*Ln];
            #pragma unroll
            for (int m = 1; m < Ln; ++m) mx = fmaxf(mx, pool[5120 + ln*Ln + m]);
            v = mx + gu_all[(h*Bn + b)*Ln + ln];
        }
        int idx = ln;
        #pragma unroll
        for (int off = 32; off > 0; off >>= 1) {
            float ov = __shfl_down(v, off);
            int oi = __shfl_down(idx, off);
            if (ov > v || (ov == v && oi < idx)) { v = ov; idx = oi; }
        }
        if (ln == 0) lstar[0] = idx;
    } else if (wv == 1) {
        float v = -3.4e38f;
        if (ln < Ln) {
            float mx = pool[5120 + ln];
            #pragma unroll
            for (int l = 1; l < Ln; ++l) mx = fmaxf(mx, pool[5120 + l*Ln + ln]);
            v = mx + gi_all[(h*Bn + b)*Ln + ln];
        }
        int idx = ln;
        #pragma unroll
        for (int off = 32; off > 0; off >>= 1) {
            float ov = __shfl_down(v, off);
            int oi = __shfl_down(idx, off);
            if (ov > v || (ov == v && oi < idx)) { v = ov; idx = oi; }
        }
        if (ln == 0) lstar[1] = idx;
    }
    __syncthreads();

    int rubase = (b*Ln + lstar[0])*Nn;
    int ribase = (b*Ln + lstar[1])*Nn;
    int r0 = ln >> 4;
    int q4 = (ln & 15) << 2;
    int idxr[25];

    if (wv < 2) {
        for (int k = tid; k < Nn*16; k += 128) {
            int n = k >> 4, qi = k & 15;
            int idx = urev[rubase + n];
            float4 v = *(const float4*)(utab + idx*Dn + (qi << 2));
            *(float4*)(pool + n*Dn + (((qi ^ (n & 15)) << 2))) = v;
        }
    } else {
        const int* rev = (wv == 2) ? irev : urev;
        const float* tab = (wv == 2) ? itab : utab;
        int rb = (wv == 2) ? ribase : rubase;
        #pragma unroll
        for (int j = 0; j < 25; ++j) idxr[j] = rev[rb + r0 + 4*j];
        float4 s = make_float4(0.f, 0.f, 0.f, 0.f);
        #pragma unroll 5
        for (int g = 0; g < 5; ++g) {
            float4 v0 = *(const float4*)(tab + idxr[g*5+0]*Dn + q4);
            float4 v1 = *(const float4*)(tab + idxr[g*5+1]*Dn + q4);
            float4 v2 = *(const float4*)(tab + idxr[g*5+2]*Dn + q4);
            float4 v3 = *(const float4*)(tab + idxr[g*5+3]*Dn + q4);
            float4 v4 = *(const float4*)(tab + idxr[g*5+4]*Dn + q4);
            s.x += v0.x+v1.x+v2.x+v3.x+v4.x;
            s.y += v0.y+v1.y+v2.y+v3.y+v4.y;
            s.z += v0.z+v1.z+v2.z+v3.z+v4.z;
            s.w += v0.w+v1.w+v2.w+v3.w+v4.w;
        }
        s.x += __shfl_xor(s.x, 16); s.y += __shfl_xor(s.y, 16); s.z += __shfl_xor(s.z, 16); s.w += __shfl_xor(s.w, 16);
        s.x += __shfl_xor(s.x, 32); s.y += __shfl_xor(s.y, 32); s.z += __shfl_xor(s.z, 32); s.w += __shfl_xor(s.w, 32);
        if (ln < 16) {
            float4 m = make_float4(s.x*(1.f/Nn), s.y*(1.f/Nn), s.z*(1.f/Nn), s.w*(1.f/Nn));
            *(float4*)(&vecs[(wv == 2) ? 1 : 0][q4]) = m;
        }
    }
    __syncthreads();

    if (tid < Dn) {
        float a = gu_v[h*Dn + tid];
        for (int bb = 0; bb < Dn; ++bb) a += GuT[h*4096 + bb*Dn + tid] * vecs[1][bb];
        vecs[2][tid] = a;
    } else if (tid < 2*Dn) {
        int aa = tid - Dn;
        float a = gi_v[h*Dn + aa];
        for (int bb = 0; bb < Dn; ++bb) a += GiT[h*4096 + bb*Dn + aa] * vecs[0][bb];
        vecs[3][aa] = a;
    }
    __syncthreads();

    if (tid < Nn) {
        float a = 0.f;
        const float* row = pool + tid*Dn;
        int sw = tid & 15;
        #pragma unroll
        for (int qi = 0; qi < 16; ++qi) {
            float4 w = *(const float4*)(&vecs[2][qi << 2]);
            float4 x = *(const float4*)(row + ((qi ^ sw) << 2));
            a += x.x*w.x + x.y*w.y + x.z*w.z + x.w*w.w;
        }
        sc[0][tid] = a;
    } else if (wv == 2) {
        float4 wq = *(const float4*)(&vecs[3][q4]);
        #pragma unroll 5
        for (int g = 0; g < 5; ++g) {
            float p0, p1, p2, p3, p4;
            {
                float4 v0 = *(const float4*)(itab + idxr[g*5+0]*Dn + q4);
                float4 v1 = *(const float4*)(itab + idxr[g*5+1]*Dn + q4);
                float4 v2 = *(const float4*)(itab + idxr[g*5+2]*Dn + q4);
                float4 v3 = *(const float4*)(itab + idxr[g*5+3]*Dn + q4);
                float4 v4 = *(const float4*)(itab + idxr[g*5+4]*Dn + q4);
                p0 = v0.x*wq.x + v0.y*wq.y + v0.z*wq.z + v0.w*wq.w;
                p1 = v1.x*wq.x + v1.y*wq.y + v1.z*wq.z + v1.w*wq.w;
                p2 = v2.x*wq.x + v2.y*wq.y + v2.z*wq.z + v2.w*wq.w;
                p3 = v3.x*wq.x + v3.y*wq.y + v3.z*wq.z + v3.w*wq.w;
                p4 = v4.x*wq.x + v4.y*wq.y + v4.z*wq.z + v4.w*wq.w;
            }
            #pragma unroll
            for (int off = 1; off < 16; off <<= 1) {
                p0 += __shfl_xor(p0, off); p1 += __shfl_xor(p1, off);
                p2 += __shfl_xor(p2, off); p3 += __shfl_xor(p3, off);
                p4 += __shfl_xor(p4, off);
            }
            if ((ln & 15) == 0) {
                sc[1][r0 + 4*(g*5+0)] = p0;
                sc[1][r0 + 4*(g*5+1)] = p1;
                sc[1][r0 + 4*(g*5+2)] = p2;
                sc[1][r0 + 4*(g*5+3)] = p3;
                sc[1][r0 + 4*(g*5+4)] = p4;
            }
        }
    }
    __syncthreads();
    if (wv == 0 || wv == 2) {
        float* s = sc[wv >> 1];
        float x0 = s[ln];
        float x1 = (ln < Nn - 64) ? s[64 + ln] : -3.4e38f;
        float mx = fmaxf(x0, x1);
        #pragma unroll
        for (int off = 32; off > 0; off >>= 1) mx = fmaxf(mx, __shfl_xor(mx, off));
        float e0 = expf(x0 - mx);
        float e1 = (ln < Nn - 64) ? expf(x1 - mx) : 0.f;
        float sum = e0 + e1;
        #pragma unroll
        for (int off = 32; off > 0; off >>= 1) sum += __shfl_xor(sum, off);
        float inv = 1.f / sum;
        s[ln] = e0 * inv;
        if (ln < Nn - 64) s[64 + ln] = e1 * inv;
    }
    __syncthreads();
    if (tid < 2*Dn) {
        int which = tid >> 6;
        int d = tid & 63;
        int qt = (d >> 2), dl = d & 3;
        const float* p = sc[which];
        float a = 0.f;
        for (int n = 0; n < Nn; ++n)
            a += p[n] * pool[n*Dn + ((qt ^ (n & 15)) << 2) + dl];
        uif[which][d] = a;
    }
    __syncthreads();
    float* fe_ = pool;
    float* re_ = pool + 128;
    float* u3_ = pool + 192;
    float* i3_ = pool + 256;
    float* A3_ = pool + 384;
    if (tid < En) {
        float a = ufc_bv[tid];
        for (int d = 0; d < Dn; ++d) a += uif[0][d] * ufcT[d*En + tid];
        re_[tid] = fmaxf(a, 0.f);
    } else if (tid < 2*En) {
        int e = tid - En;
        float a = ifc_bv[e];
        for (int d = 0; d < Dn; ++d) a += uif[1][d] * ifcT[d*En + e];
        re_[En + e] = fmaxf(a, 0.f);
    } else if (tid < 2*En + 4*En) {
        int j = tid - 2*En;
        int rrow = j >> 5, e = j & 31;
        float v;
        if (rrow == 0) v = uid_tab[uids[b]*En + e];
        else if (rrow == 1) v = iid_tab[iids[b]*En + e];
        else if (rrow == 2) v = type_tab[ttype[b]*En + e];
        else v = month_tab[tmonth[b]*En + e];
        fe_[j] = v;
    }
    __syncthreads();
    const float* WuTf = WuT_f + h*En*En;
    const float* WiTf = WiT_f + h*En*En;
    const float* Mf   = M_f  + h*En*En;
    if (tid < 2*En) {
        int l = tid >> 5, e = tid & 31;
        float a = bu_f[h*En + e];
        for (int j = 0; j < En; ++j) a += re_[l*En + j] * WuTf[j*En + e];
        u3_[tid] = a;
    } else if (tid < 6*En) {
        int t2 = tid - 2*En;
        int m = t2 >> 5, e = t2 & 31;
        float a = bi_f[h*En + e];
        for (int j = 0; j < En; ++j) a += fe_[m*En + j] * WiTf[j*En + e];
        i3_[t2] = a;
    }
    __syncthreads();
    if (tid < 2*En) {
        int l = tid >> 5, e = tid & 31;
        float a = 0.f;
        for (int d = 0; d < En; ++d) a += u3_[l*En + d] * Mf[d*En + e];
        A3_[tid] = a;
    }
    __syncthreads();
    if (tid == 0) {
        float S3[2][4];
        for (int l = 0; l < 2; ++l)
            for (int m = 0; m < 4; ++m) {
                float a = 0.f;
                for (int e = 0; e < En; ++e) a += A3_[l*En + e] * i3_[m*En + e];
                S3[l][m] = a;
            }
        float us0 = (S3[0][0] + S3[0][1] + S3[0][2] + S3[0][3]) * 0.25f;
        float us1 = (S3[1][0] + S3[1][1] + S3[1][2] + S3[1][3]) * 0.25f;
        float mx = fmaxf(us0, us1);
        float e0 = expf(us0 - mx), e1 = expf(us1 - mx);
        float inv = 1.f / (e0 + e1);
        att[0] = e0 * inv; att[1] = e1 * inv;
        float is_[4]; float mxi = -3.4e38f;
        for (int m = 0; m < 4; ++m) { is_[m] = (S3[0][m] + S3[1][m]) * 0.5f; mxi = fmaxf(mxi, is_[m]); }
        float ssum = 0.f, ee[4];
        for (int m = 0; m < 4; ++m) { ee[m] = expf(is_[m] - mxi); ssum += ee[m]; }
        float invi = 1.f / ssum;
        for (int m = 0; m < 4; ++m) att[2 + m] = ee[m] * invi;
    }
    __syncthreads();
    if (tid < En) {
        feas[b*96 + h*En + tid] = re_[tid] * att[0];
    }
    if (h == 2) {
        if (tid >= 32 && tid < 64)        { int e = tid - 32;  outp[b*96 + e]              = fe_[e]      * att[2]; }
        else if (tid >= 64 && tid < 96)   { int e = tid - 64;  outp[b*96 + 32 + e]         = fe_[64 + e] * att[4]; }
        else if (tid >= 96 && tid < 128)  { int e = tid - 96;  outp[Bn*96 + b*96 + e]      = fe_[32 + e] * att[3]; }
        else if (tid >= 128 && tid < 160) { int e = tid - 128; outp[Bn*96 + b*96 + 32 + e] = fe_[96 + e] * att[5]; }
    }
}

// ---------------- K3: final linears ----------------
__global__ __launch_bounds__(64) void k3_final(
    const float* __restrict__ feas,
    const float* __restrict__ u_fcT, const float* __restrict__ u_fc_bv,
    const float* __restrict__ i_fcT, const float* __restrict__ i_fc_bv,
    float* __restrict__ outp)
{
    __shared__ float f[96];
    int b = blockIdx.x, tid = threadIdx.x;
    for (int k = tid; k < 96; k += 64) f[k] = feas[b*96 + k];
    __syncthreads();
    if (tid < 32) {
        float a = u_fc_bv[tid];
        for (int k = 0; k < 96; ++k) a += f[k] * u_fcT[k*32 + tid];
        outp[b*96 + 64 + tid] = a;
    } else {
        int e = tid - 32;
        float a = i_fc_bv[e];
        for (int k = 0; k < 96; ++k) a += f[k] * i_fcT[k*32 + e];
        outp[Bn*96 + b*96 + 64 + e] = a;
    }
}

extern "C" void kernel_launch(void* const* d_in, const int* in_sizes, int n_in,
                              void* d_out, int out_size, void* d_ws, size_t ws_size,
                              hipStream_t stream)
{
    const int* urev = (const int*)d_in[0];
    const int* irev = (const int*)d_in[1];
    const int* uids = (const int*)d_in[2];
    const int* iids = (const int*)d_in[3];
    const int* ttype = (const int*)d_in[4];
    const int* tmonth = (const int*)d_in[5];
    const float* gu = (const float*)d_in[6];
    const float* gi = (const float*)d_in[7];
    const float* utab = (const float*)d_in[8];
    const float* itab = (const float*)d_in[9];
    const float* uid_tab = (const float*)d_in[10];
    const float* iid_tab = (const float*)d_in[11];
    const float* type_tab = (const float*)d_in[12];
    const float* month_tab = (const float*)d_in[13];
    const float* fc_g1_w = (const float*)d_in[14];
    const float* fc_g1_b = (const float*)d_in[15];
    const float* fc_g2_w = (const float*)d_in[16];
    const float* fc_g2_b = (const float*)d_in[17];
    const float* M_r = (const float*)d_in[18];
    const float* Wu_r = (const float*)d_in[19];
    const float* bu_r = (const float*)d_in[20];
    const float* Wi_r = (const float*)d_in[21];
    const float* bi_r = (const float*)d_in[22];
    const float* M_w = (const float*)d_in[23];
    const float* Wu_w = (const float*)d_in[24];
    const float* bu_w = (const float*)d_in[25];
    const float* Wi_w = (const float*)d_in[26];
    const float* bi_w = (const float*)d_in[27];
    const float* M_f = (const float*)d_in[28];
    const float* Wu_f = (const float*)d_in[29];
    const float* bu_f = (const float*)d_in[30];
    const float* Wi_f = (const float*)d_in[31];
    const float* bi_f = (const float*)d_in[32];
    const float* ufc_w = (const float*)d_in[33];
    const float* ufc_b = (const float*)d_in[34];
    const float* ifc_w = (const float*)d_in[35];
    const float* ifc_b = (const float*)d_in[36];
    const float* u_fc_w = (const float*)d_in[37];
    const float* u_fc_b = (const float*)d_in[38];
    const float* i_fc_w = (const float*)d_in[39];
    const float* i_fc_b = (const float*)d_in[40];
    (void)in_sizes; (void)n_in; (void)out_size; (void)ws_size;

    float* ws = (float*)d_ws;
    float* ugo   = ws;
    float* igo   = ugo + Bn*Ln*Dn;
    float* feas  = igo + Bn*Ln*Dn;
    float* WiT_r = feas + Bn*96;
    float* WMr   = WiT_r + Hn*Dn*Dn;
    float* bMr   = WMr + Hn*Dn*Dn;
    float* GuT   = bMr + Hn*Dn;
    float* GiT   = GuT + Hn*Dn*Dn;
    float* gu_v  = GiT + Hn*Dn*Dn;
    float* gi_v  = gu_v + Hn*Dn;
    float* WuT_f = gi_v + Hn*Dn;
    float* WiT_f = WuT_f + Hn*En*En;
    float* ufcT  = WiT_f + Hn*En*En;
    float* ifcT  = ufcT + Dn*En;
    float* u_fcT = ifcT + Dn*En;
    float* i_fcT = u_fcT + 96*En;

    hipLaunchKernelGGL(k0_all, dim3(203), dim3(256), 0, stream,
        M_r, Wu_r, bu_r, Wi_r, M_w, Wu_w, bu_w, Wi_w, bi_w,
        Wu_f, Wi_f, ufc_w, ifc_w, u_fc_w, i_fc_w,
        WMr, bMr, GuT, GiT, gu_v, gi_v, WiT_r,
        WuT_f, WiT_f, ufcT, ifcT, u_fcT, i_fcT);

    hipLaunchKernelGGL(k1_gate2, dim3(1280), dim3(256), 0, stream,
        urev, irev, utab, itab, fc_g1_w, fc_g1_b, fc_g2_w, fc_g2_b, ugo, igo);

    hipLaunchKernelGGL(k2_coatt, dim3(Bn*Hn), dim3(256), 0, stream,
        urev, irev, uids, iids, ttype, tmonth, gu, gi, utab, itab,
        uid_tab, iid_tab, type_tab, month_tab, ugo, igo,
        WMr, bMr, WiT_r, bi_r, GuT, GiT, gu_v, gi_v,
        M_f, bu_f, bi_f, WuT_f, WiT_f,
        ufcT, ufc_b, ifcT, ifc_b, feas, (float*)d_out);

    hipLaunchKernelGGL(k3_final, dim3(Bn), dim3(64), 0, stream,
        feas, u_fcT, u_fc_b, i_fcT, i_fc_b, (float*)d_out);
}

// Round 10
// 289.344 us; speedup vs baseline: 1.2010x; 1.0113x over previous
//
#include <hip/hip_runtime.h>
#include <math.h>

#define Bn 512
#define Ln 20
#define Nn 100
#define Dn 64
#define En 32
#define Hn 3

// per-wave slab offsets (floats)
#define AB_  0
#define IV_  1280
#define SS_  2560
#define SC_  2960
#define VB_  3160   // wbaru 0 | wbari 64 | wu 128 | wi 192
#define UIF_ 3416
#define RE_  3544
#define U3_  3608
#define I3_  3672
#define A3_  3800
#define ATT_ 3864
#define SLABN 3872

// ---------------- K0_all: all weight prep in ONE launch (203 blocks) ----------------
__global__ __launch_bounds__(256) void k0_all(
    const float* __restrict__ M_r, const float* __restrict__ Wu_r, const float* __restrict__ bu_r,
    const float* __restrict__ Wi_r,
    const float* __restrict__ M_w, const float* __restrict__ Wu_w, const float* __restrict__ bu_w,
    const float* __restrict__ Wi_w, const float* __restrict__ bi_w,
    const float* __restrict__ Wu_f, const float* __restrict__ Wi_f,
    const float* __restrict__ ufc, const float* __restrict__ ifc,
    const float* __restrict__ ufc2, const float* __restrict__ ifc2,
    float* __restrict__ WMr, float* __restrict__ bMr,
    float* __restrict__ GuT, float* __restrict__ GiT,
    float* __restrict__ gu_v, float* __restrict__ gi_v,
    float* __restrict__ WiT_r,
    float* __restrict__ WuT_f, float* __restrict__ WiT_f,
    float* __restrict__ ufcT, float* __restrict__ ifcT,
    float* __restrict__ u_fcT, float* __restrict__ i_fcT)
{
    __shared__ float tbuf[4][64];
    int tid = threadIdx.x, ln = tid & 63, wv = tid >> 6;
    int blk = blockIdx.x;
    if (blk < 48) {
        int W = blk*4 + wv;
        int h = W >> 6, c = W & 63;
        const float* Wu = Wu_r + h*4096;
        const float* M  = M_r  + h*4096;
        float s = 0.f;
        for (int d = 0; d < 64; ++d) s += Wu[d*64 + c] * M[d*64 + ln];
        WMr[h*4096 + c*64 + ln] = s;
    } else if (blk < 51) {
        int h = blk - 48;
        if (wv == 0) {
            float s = 0.f;
            for (int d = 0; d < 64; ++d) s += bu_r[h*64 + d] * M_r[h*4096 + d*64 + ln];
            bMr[h*64 + ln] = s;
        }
    } else if (blk < 147) {
        int W = (blk - 51)*4 + wv;
        int isGi = (W >= 192);
        int W2 = W - (isGi ? 192 : 0);
        int h = W2 >> 6, a = W2 & 63;
        float t;
        if (!isGi) {
            const float* Wu = Wu_w + h*4096; const float* M = M_w + h*4096;
            t = 0.f;
            for (int d = 0; d < 64; ++d) t += Wu[d*64 + a] * M[d*64 + ln];
        } else {
            const float* Wi = Wi_w + h*4096; const float* M = M_w + h*4096;
            t = 0.f;
            for (int d = 0; d < 64; ++d) t += M[ln*64 + d] * Wi[d*64 + a];
        }
        tbuf[wv][ln] = t;
        const float* Wsec = (isGi ? Wu_w : Wi_w) + h*4096;
        const float* bsec = (isGi ? bu_w : bi_w) + h*64;
        float s = 0.f, gvv = 0.f;
        for (int e = 0; e < 64; ++e) {
            float te = tbuf[wv][e];
            s   += te * Wsec[e*64 + ln];
            gvv += te * bsec[e];
        }
        (isGi ? GiT : GuT)[h*4096 + ln*64 + a] = s;
        if (ln == 0) (isGi ? gi_v : gu_v)[h*64 + a] = gvv;
    } else if (blk < 195) {
        int k = (blk - 147)*256 + tid;
        int h = k >> 12, r = k & 4095, c = r >> 6, dp = r & 63;
        WiT_r[k] = Wi_r[h*4096 + dp*64 + c];
    } else {
        int t = (blk - 195)*256 + tid;
        int stride = 8*256;
        for (int k = t; k < Hn*En*En; k += stride) {
            int h = k/(En*En); int rem = k - h*En*En;
            int aa = rem >> 5, c = rem & 31;
            int src = h*En*En + c*En + aa;
            WuT_f[k] = Wu_f[src]; WiT_f[k] = Wi_f[src];
        }
        for (int k = t; k < Dn*En; k += stride) {
            int d = k >> 5, e = k & 31;
            ufcT[k] = ufc[e*Dn + d]; ifcT[k] = ifc[e*Dn + d];
        }
        for (int k = t; k < 96*En; k += stride) {
            int kk = k >> 5, e = k & 31;
            u_fcT[k] = ufc2[e*96 + kk]; i_fcT[k] = ifc2[e*96 + kk];
        }
    }
}

// ---------------- K1: fused gather-sum + gate MLP (unchanged from R9) ----------------
__global__ __launch_bounds__(256) void k1_gate2(
    const int* __restrict__ urev, const int* __restrict__ irev,
    const float* __restrict__ utab, const float* __restrict__ itab,
    const float* __restrict__ W1, const float* __restrict__ b1v,
    const float* __restrict__ W2, const float* __restrict__ b2v,
    float* __restrict__ ugo, float* __restrict__ igo)
{
    __shared__ float w1s[Dn][Dn+1];
    __shared__ float w2s[Dn][Dn+1];
    __shared__ float rowb[4][Dn];
    int tid = threadIdx.x;
    for (int k = tid; k < Dn*Dn; k += 256) {
        w1s[k>>6][k&63] = W1[k];
        w2s[k>>6][k&63] = W2[k];
    }
    __syncthreads();
    int ln = tid & 63, wv = tid >> 6;
    int wid = blockIdx.x * 4 + wv;
    int r0 = ln >> 4, q4 = (ln & 15) << 2;
    float b1 = b1v[ln], b2 = b2v[ln];
    #pragma unroll 1
    for (int it = 0; it < 4; ++it) {
        int gw = wid + it * 5120;
        int side = (gw >= Bn*Ln);
        int r = gw - (side ? Bn*Ln : 0);
        const int* rev = side ? irev : urev;
        const float* tab = side ? itab : utab;
        int i0 = rev[r*Nn + ln];
        int i1 = (ln < Nn - 64) ? rev[r*Nn + 64 + ln] : 0;
        float4 buf[25];
        #pragma unroll
        for (int j = 0; j < 25; ++j) {
            int n = r0 + 4*j;
            int idx = (n < 64) ? __shfl(i0, n) : __shfl(i1, n - 64);
            buf[j] = *(const float4*)(tab + idx*Dn + q4);
        }
        float4 a = buf[0];
        #pragma unroll
        for (int j = 1; j < 25; ++j) { a.x += buf[j].x; a.y += buf[j].y; a.z += buf[j].z; a.w += buf[j].w; }
        a.x += __shfl_xor(a.x, 16); a.y += __shfl_xor(a.y, 16); a.z += __shfl_xor(a.z, 16); a.w += __shfl_xor(a.w, 16);
        a.x += __shfl_xor(a.x, 32); a.y += __shfl_xor(a.y, 32); a.z += __shfl_xor(a.z, 32); a.w += __shfl_xor(a.w, 32);
        if (ln < 16) *(float4*)(&rowb[wv][q4]) = a;
        float t1 = b1, t2 = b2;
        #pragma unroll 8
        for (int d = 0; d < Dn; ++d) {
            float sd = rowb[wv][d];
            t1 += sd * w1s[ln][d];
            t2 += sd * w2s[ln][d];
        }
        float g = (1.f / (1.f + expf(-t1))) * tanhf(t2);
        (side ? igo : ugo)[r*Dn + ln] = g;
    }
}

// ---------------- K2_fused: wave-per-(b,h), 2 barriers, k3 fused ----------------
// 512 blocks (one per b), 256 threads. Waves 0-2 run head h=wv start-to-finish
// with intra-wave exchanges through a private LDS slab; wave 3 stages fe.
__global__ __launch_bounds__(256, 2) void k2_fused(
    const int* __restrict__ urev, const int* __restrict__ irev,
    const int* __restrict__ uids, const int* __restrict__ iids,
    const int* __restrict__ ttype, const int* __restrict__ tmonth,
    const float* __restrict__ gu_all, const float* __restrict__ gi_all,
    const float* __restrict__ utab, const float* __restrict__ itab,
    const float* __restrict__ uid_tab, const float* __restrict__ iid_tab,
    const float* __restrict__ type_tab, const float* __restrict__ month_tab,
    const float* __restrict__ ug_in, const float* __restrict__ ig_in,
    const float* __restrict__ WMr, const float* __restrict__ bMr,
    const float* __restrict__ WiT_r, const float* __restrict__ bi_r,
    const float* __restrict__ GuT, const float* __restrict__ GiT,
    const float* __restrict__ gu_v, const float* __restrict__ gi_v,
    const float* __restrict__ M_f, const float* __restrict__ bu_f, const float* __restrict__ bi_f,
    const float* __restrict__ WuT_f, const float* __restrict__ WiT_f,
    const float* __restrict__ ufcT, const float* __restrict__ ufc_bv,
    const float* __restrict__ ifcT, const float* __restrict__ ifc_bv,
    const float* __restrict__ u_fcT, const float* __restrict__ u_fc_bv,
    const float* __restrict__ i_fcT, const float* __restrict__ i_fc_bv,
    float* __restrict__ outp)
{
    __shared__ __align__(16) float ug_s[Ln*Dn];
    __shared__ __align__(16) float ig_s[Ln*Dn];
    __shared__ float fe_s[4*En];
    __shared__ float fin[96];
    __shared__ __align__(16) float slab[3][SLABN];

    int tid = threadIdx.x;
    int b = blockIdx.x;
    int ln = tid & 63;
    int wv = tid >> 6;

    // ---- stage gates (all threads) + fe (wave 3) ----
    {
        const float4* su = (const float4*)(ug_in + b*Ln*Dn);
        const float4* si = (const float4*)(ig_in + b*Ln*Dn);
        for (int k = tid; k < (Ln*Dn)/4; k += 256) {
            ((float4*)ug_s)[k] = su[k];
            ((float4*)ig_s)[k] = si[k];
        }
    }
    if (wv == 3) {
        for (int k = ln; k < 4*En; k += 64) {
            int rrow = k >> 5, e = k & 31;
            float v;
            if (rrow == 0) v = uid_tab[uids[b]*En + e];
            else if (rrow == 1) v = iid_tab[iids[b]*En + e];
            else if (rrow == 2) v = type_tab[ttype[b]*En + e];
            else v = month_tab[tmonth[b]*En + e];
            fe_s[k] = v;
        }
    }
    __syncthreads();

    if (wv < 3) {
        int h = wv;
        float* sl = slab[wv];
        int r0 = ln >> 4;
        int q4 = (ln & 15) << 2;

        // ---- phase 1: ab = ug@WMr, iv = ig@WiT (per lane: output col ln, all 20 l) ----
        {
            float ab[Ln], iv[Ln];
            #pragma unroll
            for (int l = 0; l < Ln; ++l) { ab[l] = 0.f; iv[l] = 0.f; }
            const float* Wm = WMr + h*4096 + ln;
            const float* Wi = WiT_r + h*4096 + ln;
            for (int d0 = 0; d0 < Dn; d0 += 4) {
                float w0 = Wm[(d0+0)*64], w1 = Wm[(d0+1)*64], w2 = Wm[(d0+2)*64], w3 = Wm[(d0+3)*64];
                float v0 = Wi[(d0+0)*64], v1 = Wi[(d0+1)*64], v2 = Wi[(d0+2)*64], v3 = Wi[(d0+3)*64];
                #pragma unroll
                for (int l = 0; l < Ln; ++l) {
                    float4 xu = *(const float4*)(ug_s + l*Dn + d0);
                    float4 xi = *(const float4*)(ig_s + l*Dn + d0);
                    ab[l] += xu.x*w0 + xu.y*w1 + xu.z*w2 + xu.w*w3;
                    iv[l] += xi.x*v0 + xi.y*v1 + xi.z*v2 + xi.w*v3;
                }
            }
            float bA = bMr[h*64 + ln], bI = bi_r[h*64 + ln];
            #pragma unroll
            for (int l = 0; l < Ln; ++l) {
                sl[AB_ + l*64 + (ln ^ l)] = ab[l] + bA;   // XOR-swizzled rows
                sl[IV_ + l*64 + (ln ^ l)] = iv[l] + bI;
            }
        }
        // ---- S[l][m] ----
        for (int k = ln; k < Ln*Ln; k += 64) {
            int l = k / Ln, m = k - l*Ln;
            float a = 0.f;
            for (int e = 0; e < Dn; ++e)
                a += sl[AB_ + l*64 + (e ^ l)] * sl[IV_ + m*64 + (e ^ m)];
            sl[SS_ + k] = a;
        }
        // ---- argmax u (rows) then i (cols), in-wave ----
        int lu, li;
        {
            float v = -3.4e38f;
            if (ln < Ln) {
                float mx = sl[SS_ + ln*Ln];
                #pragma unroll
                for (int m = 1; m < Ln; ++m) mx = fmaxf(mx, sl[SS_ + ln*Ln + m]);
                v = mx + gu_all[(h*Bn + b)*Ln + ln];
            }
            int idx = ln;
            #pragma unroll
            for (int off = 32; off > 0; off >>= 1) {
                float ov = __shfl_down(v, off);
                int oi = __shfl_down(idx, off);
                if (ov > v || (ov == v && oi < idx)) { v = ov; idx = oi; }
            }
            lu = __shfl(idx, 0);
        }
        {
            float v = -3.4e38f;
            if (ln < Ln) {
                float mx = sl[SS_ + ln];
                #pragma unroll
                for (int l = 1; l < Ln; ++l) mx = fmaxf(mx, sl[SS_ + l*Ln + ln]);
                v = mx + gi_all[(h*Bn + b)*Ln + ln];
            }
            int idx = ln;
            #pragma unroll
            for (int off = 32; off > 0; off >>= 1) {
                float ov = __shfl_down(v, off);
                int oi = __shfl_down(idx, off);
                if (ov > v || (ov == v && oi < idx)) { v = ov; idx = oi; }
            }
            li = __shfl(idx, 0);
        }
        int rub = (b*Ln + lu)*Nn;
        int rib = (b*Ln + li)*Nn;
        int idxu[25], idxi[25];
        #pragma unroll
        for (int j = 0; j < 25; ++j) {
            idxu[j] = urev[rub + r0 + 4*j];
            idxi[j] = irev[rib + r0 + 4*j];
        }
        // ---- wbar gathers (u then i) ----
        #pragma unroll
        for (int sd = 0; sd < 2; ++sd) {
            const float* tab = sd ? itab : utab;
            const int* ix = sd ? idxi : idxu;
            float4 s = make_float4(0.f, 0.f, 0.f, 0.f);
            #pragma unroll 5
            for (int g = 0; g < 5; ++g) {
                float4 v0 = *(const float4*)(tab + ix[g*5+0]*Dn + q4);
                float4 v1 = *(const float4*)(tab + ix[g*5+1]*Dn + q4);
                float4 v2 = *(const float4*)(tab + ix[g*5+2]*Dn + q4);
                float4 v3 = *(const float4*)(tab + ix[g*5+3]*Dn + q4);
                float4 v4 = *(const float4*)(tab + ix[g*5+4]*Dn + q4);
                s.x += v0.x+v1.x+v2.x+v3.x+v4.x;
                s.y += v0.y+v1.y+v2.y+v3.y+v4.y;
                s.z += v0.z+v1.z+v2.z+v3.z+v4.z;
                s.w += v0.w+v1.w+v2.w+v3.w+v4.w;
            }
            s.x += __shfl_xor(s.x, 16); s.y += __shfl_xor(s.y, 16); s.z += __shfl_xor(s.z, 16); s.w += __shfl_xor(s.w, 16);
            s.x += __shfl_xor(s.x, 32); s.y += __shfl_xor(s.y, 32); s.z += __shfl_xor(s.z, 32); s.w += __shfl_xor(s.w, 32);
            if (ln < 16) {
                float4 m = make_float4(s.x*(1.f/Nn), s.y*(1.f/Nn), s.z*(1.f/Nn), s.w*(1.f/Nn));
                *(float4*)(&sl[VB_ + sd*64 + q4]) = m;
            }
        }
        // ---- wu = GuT^T@iwbar + gu_v ; wi = GiT^T@uwbar + gi_v ----
        {
            float a1 = gu_v[h*64 + ln], a2 = gi_v[h*64 + ln];
            for (int bb = 0; bb < 64; ++bb) {
                a1 += GuT[h*4096 + bb*64 + ln] * sl[VB_ + 64 + bb];
                a2 += GiT[h*4096 + bb*64 + ln] * sl[VB_ + bb];
            }
            sl[VB_ + 128 + ln] = a1;
            sl[VB_ + 192 + ln] = a2;
        }
        // ---- scores: regather rows, 16-lane-group dot reduce ----
        #pragma unroll
        for (int sd = 0; sd < 2; ++sd) {
            const float* tab = sd ? itab : utab;
            const int* ix = sd ? idxi : idxu;
            float4 wq = *(const float4*)(&sl[VB_ + 128 + sd*64 + q4]);
            #pragma unroll 5
            for (int j = 0; j < 25; ++j) {
                float4 v = *(const float4*)(tab + ix[j]*Dn + q4);
                float p = v.x*wq.x + v.y*wq.y + v.z*wq.z + v.w*wq.w;
                #pragma unroll
                for (int off = 1; off < 16; off <<= 1) p += __shfl_xor(p, off);
                if ((ln & 15) == 0) sl[SC_ + sd*100 + r0 + 4*j] = p;
            }
        }
        // ---- softmax over N=100 (u then i), in-wave ----
        #pragma unroll
        for (int sd = 0; sd < 2; ++sd) {
            float* s = &sl[SC_ + sd*100];
            float x0 = s[ln];
            float x1 = (ln < Nn - 64) ? s[64 + ln] : -3.4e38f;
            float mx = fmaxf(x0, x1);
            #pragma unroll
            for (int off = 32; off > 0; off >>= 1) mx = fmaxf(mx, __shfl_xor(mx, off));
            float e0 = expf(x0 - mx);
            float e1 = (ln < Nn - 64) ? expf(x1 - mx) : 0.f;
            float sum = e0 + e1;
            #pragma unroll
            for (int off = 32; off > 0; off >>= 1) sum += __shfl_xor(sum, off);
            float inv = 1.f / sum;
            s[ln] = e0 * inv;
            if (ln < Nn - 64) s[64 + ln] = e1 * inv;
        }
        // ---- PV: uif_u/uif_i both from uw (reference quirk), one regather ----
        {
            float4 au = make_float4(0.f,0.f,0.f,0.f), ai = make_float4(0.f,0.f,0.f,0.f);
            #pragma unroll 5
            for (int j = 0; j < 25; ++j) {
                int n = r0 + 4*j;
                float4 v = *(const float4*)(utab + idxu[j]*Dn + q4);
                float pu = sl[SC_ + n];
                float pi = sl[SC_ + 100 + n];
                au.x += pu*v.x; au.y += pu*v.y; au.z += pu*v.z; au.w += pu*v.w;
                ai.x += pi*v.x; ai.y += pi*v.y; ai.z += pi*v.z; ai.w += pi*v.w;
            }
            au.x += __shfl_xor(au.x,16); au.y += __shfl_xor(au.y,16); au.z += __shfl_xor(au.z,16); au.w += __shfl_xor(au.w,16);
            au.x += __shfl_xor(au.x,32); au.y += __shfl_xor(au.y,32); au.z += __shfl_xor(au.z,32); au.w += __shfl_xor(au.w,32);
            ai.x += __shfl_xor(ai.x,16); ai.y += __shfl_xor(ai.y,16); ai.z += __shfl_xor(ai.z,16); ai.w += __shfl_xor(ai.w,16);
            ai.x += __shfl_xor(ai.x,32); ai.y += __shfl_xor(ai.y,32); ai.z += __shfl_xor(ai.z,32); ai.w += __shfl_xor(ai.w,32);
            if (ln < 16) {
                *(float4*)(&sl[UIF_ + q4]) = au;
                *(float4*)(&sl[UIF_ + 64 + q4]) = ai;
            }
        }
        // ---- re = relu(fc(uif)) : lanes 0-31 u, 32-63 i ----
        {
            int e = ln & 31;
            int sd = ln >> 5;
            const float* T = sd ? ifcT : ufcT;
            float a = (sd ? ifc_bv : ufc_bv)[e];
            for (int d = 0; d < Dn; ++d) a += sl[UIF_ + sd*64 + d] * T[d*En + e];
            sl[RE_ + ln] = fmaxf(a, 0.f);
        }
        // ---- phase 3 ----
        const float* WuTf = WuT_f + h*En*En;
        const float* WiTf = WiT_f + h*En*En;
        const float* Mf   = M_f  + h*En*En;
        {
            int l = ln >> 5, e = ln & 31;
            float a = bu_f[h*En + e];
            for (int j = 0; j < En; ++j) a += sl[RE_ + l*En + j] * WuTf[j*En + e];
            sl[U3_ + ln] = a;
            #pragma unroll
            for (int mm = 0; mm < 2; ++mm) {
                int m = mm*2 + l;
                float c = bi_f[h*En + e];
                for (int j = 0; j < En; ++j) c += fe_s[m*En + j] * WiTf[j*En + e];
                sl[I3_ + m*En + e] = c;
            }
            float a3 = 0.f;
            for (int d = 0; d < En; ++d) a3 += sl[U3_ + l*En + d] * Mf[d*En + e];
            sl[A3_ + ln] = a3;
        }
        if (ln < 8) {
            int l = ln >> 2, m = ln & 3;
            float a = 0.f;
            for (int e = 0; e < En; ++e) a += sl[A3_ + l*En + e] * sl[I3_ + m*En + e];
            sl[SS_ + ln] = a;   // reuse SS as S3 scratch
        }
        if (ln == 0) {
            float S3[2][4];
            for (int l = 0; l < 2; ++l)
                for (int m = 0; m < 4; ++m) S3[l][m] = sl[SS_ + l*4 + m];
            float us0 = (S3[0][0]+S3[0][1]+S3[0][2]+S3[0][3]) * 0.25f;
            float us1 = (S3[1][0]+S3[1][1]+S3[1][2]+S3[1][3]) * 0.25f;
            float mx = fmaxf(us0, us1);
            float e0 = expf(us0 - mx), e1 = expf(us1 - mx);
            float inv = 1.f / (e0 + e1);
            sl[ATT_ + 0] = e0 * inv; sl[ATT_ + 1] = e1 * inv;
            float is_[4]; float mxi = -3.4e38f;
            for (int m = 0; m < 4; ++m) { is_[m] = (S3[0][m] + S3[1][m]) * 0.5f; mxi = fmaxf(mxi, is_[m]); }
            float ssum = 0.f, ee[4];
            for (int m = 0; m < 4; ++m) { ee[m] = expf(is_[m] - mxi); ssum += ee[m]; }
            float invi = 1.f / ssum;
            for (int m = 0; m < 4; ++m) sl[ATT_ + 2 + m] = ee[m] * invi;
        }
        if (ln < En) {
            fin[wv*En + ln] = sl[RE_ + ln] * sl[ATT_ + 0];
        }
        if (h == 2) {      // last-h fea_att outputs
            for (int k = ln; k < 128; k += 64) {
                int rrow = k >> 5, e = k & 31;
                float v = fe_s[rrow*En + e] * sl[ATT_ + 2 + rrow];
                if (rrow == 0)      outp[b*96 + e] = v;
                else if (rrow == 1) outp[Bn*96 + b*96 + e] = v;
                else if (rrow == 2) outp[b*96 + 32 + e] = v;
                else                outp[Bn*96 + b*96 + 32 + e] = v;
            }
        }
    }
    __syncthreads();
    // ---- fused k3: u_out / i_out from fin[96] ----
    if (tid < 64) {
        int e = tid & 31, sd = tid >> 5;
        const float* T = sd ? i_fcT : u_fcT;
        float a = (sd ? i_fc_bv : u_fc_bv)[e];
        for (int k = 0; k < 96; ++k) a += fin[k] * T[k*32 + e];
        outp[(sd ? Bn*96 : 0) + b*96 + 64 + e] = a;
    }
}

extern "C" void kernel_launch(void* const* d_in, const int* in_sizes, int n_in,
                              void* d_out, int out_size, void* d_ws, size_t ws_size,
                              hipStream_t stream)
{
    const int* urev = (const int*)d_in[0];
    const int* irev = (const int*)d_in[1];
    const int* uids = (const int*)d_in[2];
    const int* iids = (const int*)d_in[3];
    const int* ttype = (const int*)d_in[4];
    const int* tmonth = (const int*)d_in[5];
    const float* gu = (const float*)d_in[6];
    const float* gi = (const float*)d_in[7];
    const float* utab = (const float*)d_in[8];
    const float* itab = (const float*)d_in[9];
    const float* uid_tab = (const float*)d_in[10];
    const float* iid_tab = (const float*)d_in[11];
    const float* type_tab = (const float*)d_in[12];
    const float* month_tab = (const float*)d_in[13];
    const float* fc_g1_w = (const float*)d_in[14];
    const float* fc_g1_b = (const float*)d_in[15];
    const float* fc_g2_w = (const float*)d_in[16];
    const float* fc_g2_b = (const float*)d_in[17];
    const float* M_r = (const float*)d_in[18];
    const float* Wu_r = (const float*)d_in[19];
    const float* bu_r = (const float*)d_in[20];
    const float* Wi_r = (const float*)d_in[21];
    const float* bi_r = (const float*)d_in[22];
    const float* M_w = (const float*)d_in[23];
    const float* Wu_w = (const float*)d_in[24];
    const float* bu_w = (const float*)d_in[25];
    const float* Wi_w = (const float*)d_in[26];
    const float* bi_w = (const float*)d_in[27];
    const float* M_f = (const float*)d_in[28];
    const float* Wu_f = (const float*)d_in[29];
    const float* bu_f = (const float*)d_in[30];
    const float* Wi_f = (const float*)d_in[31];
    const float* bi_f = (const float*)d_in[32];
    const float* ufc_w = (const float*)d_in[33];
    const float* ufc_b = (const float*)d_in[34];
    const float* ifc_w = (const float*)d_in[35];
    const float* ifc_b = (const float*)d_in[36];
    const float* u_fc_w = (const float*)d_in[37];
    const float* u_fc_b = (const float*)d_in[38];
    const float* i_fc_w = (const float*)d_in[39];
    const float* i_fc_b = (const float*)d_in[40];
    (void)in_sizes; (void)n_in; (void)out_size; (void)ws_size;

    float* ws = (float*)d_ws;
    float* ugo   = ws;
    float* igo   = ugo + Bn*Ln*Dn;
    float* WiT_r = igo + Bn*Ln*Dn;
    float* WMr   = WiT_r + Hn*Dn*Dn;
    float* bMr   = WMr + Hn*Dn*Dn;
    float* GuT   = bMr + Hn*Dn;
    float* GiT   = GuT + Hn*Dn*Dn;
    float* gu_v  = GiT + Hn*Dn*Dn;
    float* gi_v  = gu_v + Hn*Dn;
    float* WuT_f = gi_v + Hn*Dn;
    float* WiT_f = WuT_f + Hn*En*En;
    float* ufcT  = WiT_f + Hn*En*En;
    float* ifcT  = ufcT + Dn*En;
    float* u_fcT = ifcT + Dn*En;
    float* i_fcT = u_fcT + 96*En;

    hipLaunchKernelGGL(k0_all, dim3(203), dim3(256), 0, stream,
        M_r, Wu_r, bu_r, Wi_r, M_w, Wu_w, bu_w, Wi_w, bi_w,
        Wu_f, Wi_f, ufc_w, ifc_w, u_fc_w, i_fc_w,
        WMr, bMr, GuT, GiT, gu_v, gi_v, WiT_r,
        WuT_f, WiT_f, ufcT, ifcT, u_fcT, i_fcT);

    hipLaunchKernelGGL(k1_gate2, dim3(1280), dim3(256), 0, stream,
        urev, irev, utab, itab, fc_g1_w, fc_g1_b, fc_g2_w, fc_g2_b, ugo, igo);

    hipLaunchKernelGGL(k2_fused, dim3(Bn), dim3(256), 0, stream,
        urev, irev, uids, iids, ttype, tmonth, gu, gi, utab, itab,
        uid_tab, iid_tab, type_tab, month_tab, ugo, igo,
        WMr, bMr, WiT_r, bi_r, GuT, GiT, gu_v, gi_v,
        M_f, bu_f, bi_f, WuT_f, WiT_f,
        ufcT, ufc_b, ifcT, ifc_b, u_fcT, u_fc_b, i_fcT, i_fc_b,
        (float*)d_out);
}